// Round 4
// baseline (723.844 us; speedup 1.0000x reference)
//
#include <hip/hip_runtime.h>

// ---------------------------------------------------------------------------
// PINN residual via MFMA (gfx950) — R12: kill the allocator fight.
// Evidence R8..R11: any __launch_bounds__ min-waves arg => arch VGPR pinned
// at 64 + AGPR overflow + scratch spill (R11: 346 MB scratch). R12:
// __launch_bounds__(256) only (no clamp; R8 precedent: no clamp -> no spill).
// K zero-padded to 128: 4 uniform 16x16x32 K-tiles/jt, no 16x16x16 tail, no
// divergent lane<16 loads. jt-outer, single (c0,c1) acc pair (8 regs).
// LDS staging rows 136 halves (272 B) -> conflict-free A-frag rebuild;
// pad region zeroed once (padded-K MFMA reads 0 * 0-weight, never stale).
// W feed from global (L2-resident, 168 KB pre-split). Numerics = R7/R8.
// ---------------------------------------------------------------------------

using half8 = __attribute__((ext_vector_type(8))) _Float16;
using f32x4 = __attribute__((ext_vector_type(4))) float;

#define LW      57344     // bytes of pre-split W per layer (2 planes, K=128)
#define ROWH    136       // halves per staging row (k = 0..127 + 8 pad)
#define PLANEH  2176      // halves per plane (16 rows x 136)
#define STGH    4352      // halves per wave (2 planes)
#define NWAVES  4

union U8 { uint4 u; half8 h; };

static __device__ __forceinline__ float fast_tanh(float z) {
    float e = __expf(2.0f * z);
    return 1.0f - 2.0f * __builtin_amdgcn_rcpf(e + 1.0f);
}

static __device__ __forceinline__ void split2(float v, _Float16& h0, _Float16& h1) {
    h0 = (_Float16)v;
    h1 = (_Float16)((v - (float)h0) * 512.0f);
}

// --------------------------- W pre-split kernel ----------------------------
// Layout per layer: [kt:4][jt:7][plane:2][lane:64][i:8] halves; k=32kt+8q+i,
// j=16jt+c15; zero for j>=100 or k>=100.
__global__ void prep_w(const float* __restrict__ W2, const float* __restrict__ W3,
                       const float* __restrict__ W4, unsigned short* __restrict__ ws) {
    int bid = blockIdx.x;
    int l = bid / 28, rem = bid % 28, kt = rem / 7, jt = rem % 7;
    const float* W = (l == 0) ? W2 : (l == 1) ? W3 : W4;
    int lane = threadIdx.x;
    int c = lane & 15, q = lane >> 4;
    int j = 16 * jt + c;
    for (int s = 0; s < 2; ++s)
        for (int i = 0; i < 8; ++i) {
            int k = 32 * kt + 8 * q + i;                   // 0..127
            float w = (j < 100 && k < 100) ? W[j * 100 + k] : 0.0f;
            _Float16 h0 = (_Float16)w;
            _Float16 val = (s == 0) ? h0 : (_Float16)((w - (float)h0) * 512.0f);
            ws[(l*LW + kt*14336 + jt*2048 + s*1024 + lane*16 + i*2) >> 1] =
                __builtin_bit_cast(unsigned short, val);
        }
}

// ------------------------------- main kernel -------------------------------
__global__ void __launch_bounds__(256) pinn_mfma(
    const float* __restrict__ x,  const float* __restrict__ t,
    const float* __restrict__ W1, const float* __restrict__ b1,
    const float* __restrict__ b2, const float* __restrict__ b3,
    const float* __restrict__ b4,
    const float* __restrict__ W5, const float* __restrict__ b5,
    const char* __restrict__ ws, float* __restrict__ out,
    int N, int nchunks)
{
    __shared__ __align__(16) _Float16 smem[NWAVES * STGH];
    const int tid  = threadIdx.x;
    const int w    = tid >> 6;           // wave id 0..3
    const int lane = tid & 63;
    const int c15  = lane & 15;
    const int q    = lane >> 4;

    // zero-init staging once (pad regions must stay 0; wave-private after)
    {
        uint4 z4 = (uint4){0u, 0u, 0u, 0u};
        for (int it = tid; it < (NWAVES * STGH) / 8; it += 256)
            ((uint4*)smem)[it] = z4;
        __syncthreads();
    }

    _Float16* stg = smem + w * STGH;     // [plane:2][row:16][k:136]

    half8 a0[4], a1[4];                  // A planes per K-tile (persistent per layer)

    for (int chunk = blockIdx.x; chunk < nchunks; chunk += gridDim.x) {
        const int colbase = chunk * 64 + w * 16;

        // ---------------- layer 1: direct A-frag build ----------------
        {
            int col = colbase + c15;
            int pt = col >> 2, ch = col & 3;
            int ptc = (pt < N) ? pt : (N - 1);
            float xv = x[ptc], tv = t[ptc];
            #pragma unroll
            for (int kt = 0; kt < 4; ++kt) {
                half8 v0, v1;
                #pragma unroll
                for (int i = 0; i < 8; ++i) {
                    int j = 32 * kt + 8 * q + i;           // 0..127
                    float v = 0.0f;
                    if (j < 100) {
                        float w0 = W1[2*j], w1 = W1[2*j+1], bb = b1[j];
                        float p = fmaf(w0, xv, fmaf(w1, tv, bb));
                        float a = fast_tanh(p);
                        float s = 1.0f - a * a;
                        v = (ch == 0) ? a : (ch == 1) ? s * w1
                           : (ch == 2) ? s * w0 : -2.0f * a * s * w0 * w0;
                    }
                    _Float16 h0, h1; split2(v, h0, h1);
                    v0[i] = h0; v1[i] = h1;
                }
                a0[kt] = v0; a1[kt] = v1;
            }
        }

        // ---------------- 3 hidden GEMMs + transitions ----------------
        for (int l = 0; l < 3; ++l) {
            const char* WL = ws + l * LW;
            const float* BL = (l == 0) ? b2 : (l == 1) ? b3 : b4;

            float p00 = 0.f, p01 = 0.f, p03 = 0.f;   // epilogue accumulators
            float p10 = 0.f, p11 = 0.f, p13 = 0.f;

            for (int jt = 0; jt < 7; ++jt) {
                // ---- batched B-frag loads for this jt (8 x uint4) ----
                const char* bj = WL + jt * 2048 + lane * 16;
                U8 b00, b01, b10, b11, b20, b21, b30, b31;
                b00.u = *(const uint4*)(bj + 0*14336);
                b01.u = *(const uint4*)(bj + 0*14336 + 1024);
                b10.u = *(const uint4*)(bj + 1*14336);
                b11.u = *(const uint4*)(bj + 1*14336 + 1024);
                b20.u = *(const uint4*)(bj + 2*14336);
                b21.u = *(const uint4*)(bj + 2*14336 + 1024);
                b30.u = *(const uint4*)(bj + 3*14336);
                b31.u = *(const uint4*)(bj + 3*14336 + 1024);

                // ---- single accumulator pair for this jt ----
                f32x4 c0 = (f32x4){0.f, 0.f, 0.f, 0.f};
                f32x4 c1 = (f32x4){0.f, 0.f, 0.f, 0.f};
                c0 = __builtin_amdgcn_mfma_f32_16x16x32_f16(a0[0], b00.h, c0, 0, 0, 0);
                c1 = __builtin_amdgcn_mfma_f32_16x16x32_f16(a0[0], b01.h, c1, 0, 0, 0);
                c1 = __builtin_amdgcn_mfma_f32_16x16x32_f16(a1[0], b00.h, c1, 0, 0, 0);
                c0 = __builtin_amdgcn_mfma_f32_16x16x32_f16(a0[1], b10.h, c0, 0, 0, 0);
                c1 = __builtin_amdgcn_mfma_f32_16x16x32_f16(a0[1], b11.h, c1, 0, 0, 0);
                c1 = __builtin_amdgcn_mfma_f32_16x16x32_f16(a1[1], b10.h, c1, 0, 0, 0);
                c0 = __builtin_amdgcn_mfma_f32_16x16x32_f16(a0[2], b20.h, c0, 0, 0, 0);
                c1 = __builtin_amdgcn_mfma_f32_16x16x32_f16(a0[2], b21.h, c1, 0, 0, 0);
                c1 = __builtin_amdgcn_mfma_f32_16x16x32_f16(a1[2], b20.h, c1, 0, 0, 0);
                c0 = __builtin_amdgcn_mfma_f32_16x16x32_f16(a0[3], b30.h, c0, 0, 0, 0);
                c1 = __builtin_amdgcn_mfma_f32_16x16x32_f16(a0[3], b31.h, c1, 0, 0, 0);
                c1 = __builtin_amdgcn_mfma_f32_16x16x32_f16(a1[3], b30.h, c1, 0, 0, 0);

                // ---- consume immediately ----
                int j  = 16 * jt + c15;
                float z0 = c0[0] + c1[0] * (1.0f/512.0f);
                float z1 = c0[1] + c1[1] * (1.0f/512.0f);
                float z2 = c0[2] + c1[2] * (1.0f/512.0f);
                float z3 = c0[3] + c1[3] * (1.0f/512.0f);

                if (l < 2) {
                    float bj2 = BL[(j < 100) ? j : 99];
                    float a = fast_tanh(z0 + bj2);
                    float s = 1.0f - a * a;
                    float v[4];
                    v[0] = a; v[1] = s * z1; v[2] = s * z2;
                    v[3] = fmaf(-2.0f * a * s * z2, z2, s * z3);
                    #pragma unroll
                    for (int r = 0; r < 4; ++r) {
                        _Float16 h0, h1; split2(v[r], h0, h1);
                        _Float16* bp = stg + (4 * q + r) * ROWH + j;   // j <= 111 < 112-pad
                        bp[0]      = h0;
                        bp[PLANEH] = h1;
                    }
                } else {
                    int j2 = (j < 100) ? j : 99;
                    float m = (j < 100) ? 1.0f : 0.0f;
                    float bj2 = BL[j2];
                    float w50 = W5[j2] * m, w51 = W5[100 + j2] * m;
                    float a = fast_tanh(z0 + bj2);
                    float s = 1.0f - a * a;
                    float v0 = a, v1 = s * z1;
                    float v3 = fmaf(-2.0f * a * s * z2, z2, s * z3);
                    p00 = fmaf(w50, v0, p00);
                    p01 = fmaf(w50, v1, p01);
                    p03 = fmaf(w50, v3, p03);
                    p10 = fmaf(w51, v0, p10);
                    p11 = fmaf(w51, v1, p11);
                    p13 = fmaf(w51, v3, p13);
                }
            }

            if (l < 2) {
                // ---- build next-layer A-frags from full-layer staging ----
                // read 8 contiguous halves at (row=c15, k=32*kc+8*q); row
                // stride 272 B => bank period 8 with 2-way aliasing (free).
                #pragma unroll
                for (int kc = 0; kc < 4; ++kc) {
                    const _Float16* rb = stg + c15 * ROWH + 32 * kc + 8 * q;
                    U8 u;
                    uint2 L, H;
                    L = *(const uint2*)(rb);            H = *(const uint2*)(rb + 4);
                    u.u = (uint4){L.x, L.y, H.x, H.y};  a0[kc] = u.h;
                    L = *(const uint2*)(rb + PLANEH);   H = *(const uint2*)(rb + PLANEH + 4);
                    u.u = (uint4){L.x, L.y, H.x, H.y};  a1[kc] = u.h;
                }
            } else {
                // ---- reduce + NLS residual + store ----
                #pragma unroll
                for (int m = 1; m <= 8; m <<= 1) {
                    p00 += __shfl_xor(p00, m, 64);
                    p01 += __shfl_xor(p01, m, 64);
                    p03 += __shfl_xor(p03, m, 64);
                    p10 += __shfl_xor(p10, m, 64);
                    p11 += __shfl_xor(p11, m, 64);
                    p13 += __shfl_xor(p13, m, 64);
                }
                int pt = chunk * 16 + w * 4 + q;
                if (c15 == 0 && pt < N) {
                    float ur = p00 + b5[0], ui = p10 + b5[1];
                    float mag2 = ur * ur + ui * ui;
                    float fr = fmaf(mag2, ur, fmaf(0.5f, p03, -p11));
                    float fi = fmaf(mag2, ui, fmaf(0.5f, p13,  p01));
                    out[pt]     = fr;
                    out[N + pt] = fi;
                }
            }
        }
    }
}

extern "C" void kernel_launch(void* const* d_in, const int* in_sizes, int n_in,
                              void* d_out, int out_size, void* d_ws, size_t ws_size,
                              hipStream_t stream) {
    const float* x  = (const float*)d_in[0];
    const float* t  = (const float*)d_in[1];
    const float* W1 = (const float*)d_in[2];
    const float* b1 = (const float*)d_in[3];
    const float* W2 = (const float*)d_in[4];
    const float* b2 = (const float*)d_in[5];
    const float* W3 = (const float*)d_in[6];
    const float* b3 = (const float*)d_in[7];
    const float* W4 = (const float*)d_in[8];
    const float* b4 = (const float*)d_in[9];
    const float* W5 = (const float*)d_in[10];
    const float* b5 = (const float*)d_in[11];
    float* out = (float*)d_out;
    const int N = in_sizes[0];
    const int nchunks = (N + 15) / 16;       // 64 cols = 16 points per chunk

    prep_w<<<84, 64, 0, stream>>>(W2, W3, W4, (unsigned short*)d_ws);
    pinn_mfma<<<2048, 256, 0, stream>>>(x, t, W1, b1, b2, b3, b4, W5, b5,
                                        (const char*)d_ws, out, N, nchunks);
}

// Round 6
// 663.465 us; speedup vs baseline: 1.0910x; 1.0910x over previous
//
#include <hip/hip_runtime.h>

// ---------------------------------------------------------------------------
// PINN residual via MFMA (gfx950) — R14: R13 compile fix (macro name capture
// + OOB index). Structure: R8 (W in LDS, kt-outer, per-wave staging, no
// barriers) at 1024-thread blocks = 16 waves/CU (R8 had 12). Enablers:
// (1) staging window 2304->1536 B/wave (single-jt 16-kk window, 48 B rows);
// (2) acc split 4+3 jt per pass (<=32 acc regs) to fit the 128-reg cap of
// launch_bounds(1024). R9-R12 lesson: W must stay in LDS (global-W =
// L2-latency-bound, 700+ us). LDS = 134416 + 16*1536 = 158992 B.
// ---------------------------------------------------------------------------

using half8 = __attribute__((ext_vector_type(8))) _Float16;
using half4 = __attribute__((ext_vector_type(4))) _Float16;
using f32x4 = __attribute__((ext_vector_type(4))) float;

#define LW      44800     // bytes of pre-split W per layer (2 planes)
#define ZOFF    134400    // 16-byte zero block (B-frag tail, lanes>=16)
#define WINOFF  134416
#define WINW    1536      // per-wave window: 2 planes x 16 rows x 24 halves
#define ROWB    48        // window row stride (bytes)
#define PLANEB2 768       // window plane offset (bytes)
#define SMEM_BYTES 158992 // 134416 + 16*1536

union U8 { uint4 u; half8 h; };
union U4 { uint2 u; half4 h; };

static __device__ __forceinline__ float fast_tanh(float z) {
    float e = __expf(2.0f * z);
    return 1.0f - 2.0f * __builtin_amdgcn_rcpf(e + 1.0f);
}

static __device__ __forceinline__ void split2(float v, _Float16& h0, _Float16& h1) {
    h0 = (_Float16)v;
    h1 = (_Float16)((v - (float)h0) * 512.0f);
}

// --------------------------- W pre-split kernel ----------------------------
__global__ void prep_w(const float* __restrict__ W2, const float* __restrict__ W3,
                       const float* __restrict__ W4, unsigned short* __restrict__ ws) {
    int bid = blockIdx.x;
    int l = bid / 28, rem = bid % 28, kt = rem / 7, jt = rem % 7;
    const float* W = (l == 0) ? W2 : (l == 1) ? W3 : W4;
    int lane = threadIdx.x;
    int c = lane & 15, q = lane >> 4;
    int j = 16 * jt + c;
    if (kt < 3) {
        for (int s = 0; s < 2; ++s)
            for (int i = 0; i < 8; ++i) {
                int k = 32 * kt + 8 * q + i;               // <= 95
                float w = (j < 100) ? W[j * 100 + k] : 0.0f;
                _Float16 h0 = (_Float16)w;
                _Float16 val = (s == 0) ? h0 : (_Float16)((w - (float)h0) * 512.0f);
                ws[(l*LW + kt*14336 + jt*2048 + s*1024 + lane*16 + i*2) >> 1] =
                    __builtin_bit_cast(unsigned short, val);
            }
    } else if (lane < 16) {                                 // tail: k=96..99
        for (int s = 0; s < 2; ++s)
            for (int i = 0; i < 4; ++i) {
                int k = 96 + i;
                float w = (j < 100) ? W[j * 100 + k] : 0.0f;
                _Float16 h0 = (_Float16)w;
                _Float16 val = (s == 0) ? h0 : (_Float16)((w - (float)h0) * 512.0f);
                ws[(l*LW + 43008 + jt*256 + s*128 + lane*8 + i*2) >> 1] =
                    __builtin_bit_cast(unsigned short, val);
            }
    }
}

// ------------------------------- main kernel -------------------------------
__global__ void __launch_bounds__(1024) pinn_mfma(
    const float* __restrict__ x,  const float* __restrict__ t,
    const float* __restrict__ W1, const float* __restrict__ b1,
    const float* __restrict__ b2, const float* __restrict__ b3,
    const float* __restrict__ b4,
    const float* __restrict__ W5, const float* __restrict__ b5,
    const char* __restrict__ ws, float* __restrict__ out,
    int N, int nchunks)
{
    extern __shared__ char smem[];
    const int tid  = threadIdx.x;
    const int w    = tid >> 6;           // wave id 0..15
    const int lane = tid & 63;
    const int c15  = lane & 15;
    const int q    = lane >> 4;

    // stage all pre-split W into LDS (134400 B = 8400 uint4)
    for (int it = 0; it < 9; ++it) {
        int idx = tid + it * 1024;
        if (idx < 8400) ((uint4*)smem)[idx] = ((const uint4*)ws)[idx];
    }
    if (tid < 4) *(unsigned*)(smem + ZOFF + tid * 4) = 0u;
    __syncthreads();

    char* win = smem + WINOFF + w * WINW;   // [plane:2][row:16][kk:24] halves

    half8 a0[3], a1[3];                  // current-layer A planes per ktile
    half4 a0t,   a1t;                    // K-tail frags (16x16x16)
    half8 n0[3], n1[3];                  // next-layer A planes (built per jt)
    half4 n0t,   n1t;

    for (int chunk = blockIdx.x; chunk < nchunks; chunk += gridDim.x) {
        const int colbase = chunk * 256 + w * 16;

        // ---------------- layer 1: direct A-frag build ----------------
        {
            int col = colbase + c15;
            int pt = col >> 2, ch = col & 3;
            int ptc = (pt < N) ? pt : (N - 1);
            float xv = x[ptc], tv = t[ptc];
            #pragma unroll
            for (int kt = 0; kt < 3; ++kt) {
                half8 v0, v1;
                #pragma unroll
                for (int i = 0; i < 8; ++i) {
                    int j = 32 * kt + 8 * q + i;           // <= 95
                    float w0 = W1[2*j], w1 = W1[2*j+1], bb = b1[j];
                    float p = fmaf(w0, xv, fmaf(w1, tv, bb));
                    float a = fast_tanh(p);
                    float s = 1.0f - a * a;
                    float v = (ch == 0) ? a : (ch == 1) ? s * w1
                             : (ch == 2) ? s * w0 : -2.0f * a * s * w0 * w0;
                    _Float16 h0, h1; split2(v, h0, h1);
                    v0[i] = h0; v1[i] = h1;
                }
                a0[kt] = v0; a1[kt] = v1;
            }
            half4 t0 = {0, 0, 0, 0}, t1 = {0, 0, 0, 0};
            if (q == 0) {
                #pragma unroll
                for (int i = 0; i < 4; ++i) {
                    int j = 96 + i;
                    float w0 = W1[2*j], w1 = W1[2*j+1], bb = b1[j];
                    float p = fmaf(w0, xv, fmaf(w1, tv, bb));
                    float a = fast_tanh(p);
                    float s = 1.0f - a * a;
                    float v = (ch == 0) ? a : (ch == 1) ? s * w1
                             : (ch == 2) ? s * w0 : -2.0f * a * s * w0 * w0;
                    _Float16 h0, h1; split2(v, h0, h1);
                    t0[i] = h0; t1[i] = h1;
                }
            }
            a0t = t0; a1t = t1;
        }

        // ---------------- 3 hidden GEMMs + transitions ----------------
        for (int l = 0; l < 3; ++l) {
            const char* WL = smem + l * LW;
            const float* BL = (l == 0) ? b2 : (l == 1) ? b3 : b4;

            float p00 = 0.f, p01 = 0.f, p03 = 0.f;   // epilogue accumulators
            float p10 = 0.f, p11 = 0.f, p13 = 0.f;

            // consume-one-jt: transition (l<2, builds n-frags via window) or
            // epilogue partial (l==2). JT must be a LITERAL constant.
            #define CONSUME(JT, C0, C1)                                          \
            {                                                                    \
                int j  = 16 * (JT) + c15;                                        \
                float z0 = (C0)[0] + (C1)[0] * (1.0f/512.0f);                    \
                float z1 = (C0)[1] + (C1)[1] * (1.0f/512.0f);                    \
                float z2 = (C0)[2] + (C1)[2] * (1.0f/512.0f);                    \
                float z3 = (C0)[3] + (C1)[3] * (1.0f/512.0f);                    \
                if (l < 2) {                                                     \
                    float bj = BL[(j < 100) ? j : 99];                           \
                    float a = fast_tanh(z0 + bj);                                \
                    float s = 1.0f - a * a;                                      \
                    float v0 = a, v1 = s * z1, v2 = s * z2;                      \
                    float v3 = fmaf(-2.0f * a * s * z2, z2, s * z3);             \
                    _Float16 h0, h1;                                             \
                    char* bp = win + c15 * 2;                                    \
                    split2(v0, h0, h1);                                          \
                    *(_Float16*)(bp + (4*q+0)*ROWB) = h0;                        \
                    *(_Float16*)(bp + (4*q+0)*ROWB + PLANEB2) = h1;              \
                    split2(v1, h0, h1);                                          \
                    *(_Float16*)(bp + (4*q+1)*ROWB) = h0;                        \
                    *(_Float16*)(bp + (4*q+1)*ROWB + PLANEB2) = h1;              \
                    split2(v2, h0, h1);                                          \
                    *(_Float16*)(bp + (4*q+2)*ROWB) = h0;                        \
                    *(_Float16*)(bp + (4*q+2)*ROWB + PLANEB2) = h1;              \
                    split2(v3, h0, h1);                                          \
                    *(_Float16*)(bp + (4*q+3)*ROWB) = h0;                        \
                    *(_Float16*)(bp + (4*q+3)*ROWB + PLANEB2) = h1;              \
                    if ((JT) < 6) {                                              \
                        const int nidx = ((JT) < 6) ? ((JT) >> 1) : 0;           \
                        const char* rb = win + c15 * ROWB + (q & 1) * 16;        \
                        U8 mu8;                                                  \
                        bool act = ((q >> 1) == ((JT) & 1));                     \
                        mu8.u = *(const uint4*)(rb);                             \
                        if (act) n0[nidx] = mu8.h;                               \
                        mu8.u = *(const uint4*)(rb + PLANEB2);                   \
                        if (act) n1[nidx] = mu8.h;                               \
                    } else {                                                     \
                        const char* rb = win + c15 * ROWB;                       \
                        U4 mu4;                                                  \
                        mu4.u = *(const uint2*)(rb);                             \
                        n0t = (q == 0) ? mu4.h : (half4){0,0,0,0};               \
                        mu4.u = *(const uint2*)(rb + PLANEB2);                   \
                        n1t = (q == 0) ? mu4.h : (half4){0,0,0,0};               \
                    }                                                            \
                } else {                                                         \
                    int j2 = (j < 100) ? j : 99;                                 \
                    float m = (j < 100) ? 1.0f : 0.0f;                           \
                    float bj = BL[j2];                                           \
                    float w50 = W5[j2] * m, w51 = W5[100 + j2] * m;              \
                    float a = fast_tanh(z0 + bj);                                \
                    float s = 1.0f - a * a;                                      \
                    float v0 = a, v1 = s * z1;                                   \
                    float v3 = fmaf(-2.0f * a * s * z2, z2, s * z3);             \
                    p00 = fmaf(w50, v0, p00);                                    \
                    p01 = fmaf(w50, v1, p01);                                    \
                    p03 = fmaf(w50, v3, p03);                                    \
                    p10 = fmaf(w51, v0, p10);                                    \
                    p11 = fmaf(w51, v1, p11);                                    \
                    p13 = fmaf(w51, v3, p13);                                    \
                }                                                                \
            }

            // ---------------- PASS A: jt 0..3 (acc 32 regs) ----------------
            {
                f32x4 c0[4], c1[4];
                #pragma unroll
                for (int u = 0; u < 4; ++u) {
                    c0[u] = (f32x4){0.f, 0.f, 0.f, 0.f};
                    c1[u] = (f32x4){0.f, 0.f, 0.f, 0.f};
                }
                #pragma unroll
                for (int kt = 0; kt < 3; ++kt)
                    #pragma unroll
                    for (int u = 0; u < 4; ++u) {
                        U8 b0u, b1u;
                        b0u.u = *(const uint4*)(WL + kt*14336 + u*2048 + lane*16);
                        b1u.u = *(const uint4*)(WL + kt*14336 + u*2048 + 1024 + lane*16);
                        c0[u] = __builtin_amdgcn_mfma_f32_16x16x32_f16(a0[kt], b0u.h, c0[u], 0, 0, 0);
                        c1[u] = __builtin_amdgcn_mfma_f32_16x16x32_f16(a0[kt], b1u.h, c1[u], 0, 0, 0);
                        c1[u] = __builtin_amdgcn_mfma_f32_16x16x32_f16(a1[kt], b0u.h, c1[u], 0, 0, 0);
                    }
                #pragma unroll
                for (int u = 0; u < 4; ++u) {              // K-tail (k=96..99)
                    int toff  = (lane < 16) ? (l*LW + 43008 + u*256 + lane*8) : ZOFF;
                    int toff1 = (lane < 16) ? (toff + 128) : ZOFF;
                    U4 b0u, b1u;
                    b0u.u = *(const uint2*)(smem + toff);
                    b1u.u = *(const uint2*)(smem + toff1);
                    c0[u] = __builtin_amdgcn_mfma_f32_16x16x16f16(a0t, b0u.h, c0[u], 0, 0, 0);
                    c1[u] = __builtin_amdgcn_mfma_f32_16x16x16f16(a0t, b1u.h, c1[u], 0, 0, 0);
                    c1[u] = __builtin_amdgcn_mfma_f32_16x16x16f16(a1t, b0u.h, c1[u], 0, 0, 0);
                }
                CONSUME(0, c0[0], c1[0]);
                CONSUME(1, c0[1], c1[1]);
                CONSUME(2, c0[2], c1[2]);
                CONSUME(3, c0[3], c1[3]);
            }

            // ---------------- PASS B: jt 4..6 (acc 24 regs) ----------------
            {
                f32x4 c0[3], c1[3];
                #pragma unroll
                for (int u = 0; u < 3; ++u) {
                    c0[u] = (f32x4){0.f, 0.f, 0.f, 0.f};
                    c1[u] = (f32x4){0.f, 0.f, 0.f, 0.f};
                }
                #pragma unroll
                for (int kt = 0; kt < 3; ++kt)
                    #pragma unroll
                    for (int u = 0; u < 3; ++u) {
                        int jt = 4 + u;
                        U8 b0u, b1u;
                        b0u.u = *(const uint4*)(WL + kt*14336 + jt*2048 + lane*16);
                        b1u.u = *(const uint4*)(WL + kt*14336 + jt*2048 + 1024 + lane*16);
                        c0[u] = __builtin_amdgcn_mfma_f32_16x16x32_f16(a0[kt], b0u.h, c0[u], 0, 0, 0);
                        c1[u] = __builtin_amdgcn_mfma_f32_16x16x32_f16(a0[kt], b1u.h, c1[u], 0, 0, 0);
                        c1[u] = __builtin_amdgcn_mfma_f32_16x16x32_f16(a1[kt], b0u.h, c1[u], 0, 0, 0);
                    }
                #pragma unroll
                for (int u = 0; u < 3; ++u) {              // K-tail
                    int jt = 4 + u;
                    int toff  = (lane < 16) ? (l*LW + 43008 + jt*256 + lane*8) : ZOFF;
                    int toff1 = (lane < 16) ? (toff + 128) : ZOFF;
                    U4 b0u, b1u;
                    b0u.u = *(const uint2*)(smem + toff);
                    b1u.u = *(const uint2*)(smem + toff1);
                    c0[u] = __builtin_amdgcn_mfma_f32_16x16x16f16(a0t, b0u.h, c0[u], 0, 0, 0);
                    c1[u] = __builtin_amdgcn_mfma_f32_16x16x16f16(a0t, b1u.h, c1[u], 0, 0, 0);
                    c1[u] = __builtin_amdgcn_mfma_f32_16x16x16f16(a1t, b0u.h, c1[u], 0, 0, 0);
                }
                CONSUME(4, c0[0], c1[0]);
                CONSUME(5, c0[1], c1[1]);
                CONSUME(6, c0[2], c1[2]);
            }
            #undef CONSUME

            if (l < 2) {
                a0[0] = n0[0]; a0[1] = n0[1]; a0[2] = n0[2];
                a1[0] = n1[0]; a1[1] = n1[1]; a1[2] = n1[2];
                a0t = n0t; a1t = n1t;
            } else {
                // ---- reduce + NLS residual + store ----
                #pragma unroll
                for (int m = 1; m <= 8; m <<= 1) {
                    p00 += __shfl_xor(p00, m, 64);
                    p01 += __shfl_xor(p01, m, 64);
                    p03 += __shfl_xor(p03, m, 64);
                    p10 += __shfl_xor(p10, m, 64);
                    p11 += __shfl_xor(p11, m, 64);
                    p13 += __shfl_xor(p13, m, 64);
                }
                int pt = chunk * 64 + w * 4 + q;
                if (c15 == 0 && pt < N) {
                    float ur = p00 + b5[0], ui = p10 + b5[1];
                    float mag2 = ur * ur + ui * ui;
                    float fr = fmaf(mag2, ur, fmaf(0.5f, p03, -p11));
                    float fi = fmaf(mag2, ui, fmaf(0.5f, p13,  p01));
                    out[pt]     = fr;
                    out[N + pt] = fi;
                }
            }
        }
    }
}

extern "C" void kernel_launch(void* const* d_in, const int* in_sizes, int n_in,
                              void* d_out, int out_size, void* d_ws, size_t ws_size,
                              hipStream_t stream) {
    const float* x  = (const float*)d_in[0];
    const float* t  = (const float*)d_in[1];
    const float* W1 = (const float*)d_in[2];
    const float* b1 = (const float*)d_in[3];
    const float* W2 = (const float*)d_in[4];
    const float* b2 = (const float*)d_in[5];
    const float* W3 = (const float*)d_in[6];
    const float* b3 = (const float*)d_in[7];
    const float* W4 = (const float*)d_in[8];
    const float* b4 = (const float*)d_in[9];
    const float* W5 = (const float*)d_in[10];
    const float* b5 = (const float*)d_in[11];
    float* out = (float*)d_out;
    const int N = in_sizes[0];
    const int nchunks = (N + 63) / 64;       // 256 cols = 64 points per chunk

    (void)hipFuncSetAttribute((const void*)pinn_mfma,
                              hipFuncAttributeMaxDynamicSharedMemorySize, SMEM_BYTES);

    prep_w<<<84, 64, 0, stream>>>(W2, W3, W4, (unsigned short*)d_ws);
    pinn_mfma<<<256, 1024, SMEM_BYTES, stream>>>(x, t, W1, b1, b2, b3, b4, W5, b5,
                                                 (const char*)d_ws, out, N, nchunks);
}

// Round 7
// 660.940 us; speedup vs baseline: 1.0952x; 1.0038x over previous
//
#include <hip/hip_runtime.h>

// ---------------------------------------------------------------------------
// PINN residual via MFMA (gfx950) — R15: R14 frame (W in LDS, 1024-thread
// blocks = 16 waves/CU, per-wave 1536 B staging window) + R11's lean per-jt
// GEMM (single acc pair, B-temps reused) to fit the 128-reg/wave budget.
// R14 post-mortem: PASS A/B multi-acc + hoisted B-loads -> live set ~150 >
// 128 -> arch VGPR pinned 64 + 875 MB scratch traffic (= the runtime).
// Per-jt demand here: A 28 + nextA 28 + acc 8 + B 8 + misc ~25 = ~100.
// LDS = 134416 + 16*1536 = 158992 B. Numerics = R7/R8 (absmax 4.88e-4).
// ---------------------------------------------------------------------------

using half8 = __attribute__((ext_vector_type(8))) _Float16;
using half4 = __attribute__((ext_vector_type(4))) _Float16;
using f32x4 = __attribute__((ext_vector_type(4))) float;

#define LW      44800     // bytes of pre-split W per layer (2 planes)
#define ZOFF    134400    // 16-byte zero block (B-frag tail, lanes>=16)
#define WINOFF  134416
#define WINW    1536      // per-wave window: 2 planes x 16 rows x 24 halves
#define ROWB    48        // window row stride (bytes)
#define PLANEB2 768       // window plane offset (bytes)
#define SMEM_BYTES 158992 // 134416 + 16*1536

union U8 { uint4 u; half8 h; };
union U4 { uint2 u; half4 h; };

static __device__ __forceinline__ float fast_tanh(float z) {
    float e = __expf(2.0f * z);
    return 1.0f - 2.0f * __builtin_amdgcn_rcpf(e + 1.0f);
}

static __device__ __forceinline__ void split2(float v, _Float16& h0, _Float16& h1) {
    h0 = (_Float16)v;
    h1 = (_Float16)((v - (float)h0) * 512.0f);
}

// --------------------------- W pre-split kernel ----------------------------
__global__ void prep_w(const float* __restrict__ W2, const float* __restrict__ W3,
                       const float* __restrict__ W4, unsigned short* __restrict__ ws) {
    int bid = blockIdx.x;
    int l = bid / 28, rem = bid % 28, kt = rem / 7, jt = rem % 7;
    const float* W = (l == 0) ? W2 : (l == 1) ? W3 : W4;
    int lane = threadIdx.x;
    int c = lane & 15, q = lane >> 4;
    int j = 16 * jt + c;
    if (kt < 3) {
        for (int s = 0; s < 2; ++s)
            for (int i = 0; i < 8; ++i) {
                int k = 32 * kt + 8 * q + i;               // <= 95
                float w = (j < 100) ? W[j * 100 + k] : 0.0f;
                _Float16 h0 = (_Float16)w;
                _Float16 val = (s == 0) ? h0 : (_Float16)((w - (float)h0) * 512.0f);
                ws[(l*LW + kt*14336 + jt*2048 + s*1024 + lane*16 + i*2) >> 1] =
                    __builtin_bit_cast(unsigned short, val);
            }
    } else if (lane < 16) {                                 // tail: k=96..99
        for (int s = 0; s < 2; ++s)
            for (int i = 0; i < 4; ++i) {
                int k = 96 + i;
                float w = (j < 100) ? W[j * 100 + k] : 0.0f;
                _Float16 h0 = (_Float16)w;
                _Float16 val = (s == 0) ? h0 : (_Float16)((w - (float)h0) * 512.0f);
                ws[(l*LW + 43008 + jt*256 + s*128 + lane*8 + i*2) >> 1] =
                    __builtin_bit_cast(unsigned short, val);
            }
    }
}

// ------------------------------- main kernel -------------------------------
__global__ void __launch_bounds__(1024) pinn_mfma(
    const float* __restrict__ x,  const float* __restrict__ t,
    const float* __restrict__ W1, const float* __restrict__ b1,
    const float* __restrict__ b2, const float* __restrict__ b3,
    const float* __restrict__ b4,
    const float* __restrict__ W5, const float* __restrict__ b5,
    const char* __restrict__ ws, float* __restrict__ out,
    int N, int nchunks)
{
    extern __shared__ char smem[];
    const int tid  = threadIdx.x;
    const int w    = tid >> 6;           // wave id 0..15
    const int lane = tid & 63;
    const int c15  = lane & 15;
    const int q    = lane >> 4;

    // stage all pre-split W into LDS (134400 B = 8400 uint4)
    for (int it = 0; it < 9; ++it) {
        int idx = tid + it * 1024;
        if (idx < 8400) ((uint4*)smem)[idx] = ((const uint4*)ws)[idx];
    }
    if (tid < 4) *(unsigned*)(smem + ZOFF + tid * 4) = 0u;
    __syncthreads();

    char* win = smem + WINOFF + w * WINW;   // [plane:2][row:16][kk:24] halves

    half8 a0[3], a1[3];                  // current-layer A planes per ktile
    half4 a0t,   a1t;                    // K-tail frags (16x16x16)
    half8 n0[3], n1[3];                  // next-layer A planes (built per jt)
    half4 n0t,   n1t;

    for (int chunk = blockIdx.x; chunk < nchunks; chunk += gridDim.x) {
        const int colbase = chunk * 256 + w * 16;

        // ---------------- layer 1: direct A-frag build ----------------
        {
            int col = colbase + c15;
            int pt = col >> 2, ch = col & 3;
            int ptc = (pt < N) ? pt : (N - 1);
            float xv = x[ptc], tv = t[ptc];
            #pragma unroll
            for (int kt = 0; kt < 3; ++kt) {
                half8 v0, v1;
                #pragma unroll
                for (int i = 0; i < 8; ++i) {
                    int j = 32 * kt + 8 * q + i;           // <= 95
                    float w0 = W1[2*j], w1 = W1[2*j+1], bb = b1[j];
                    float p = fmaf(w0, xv, fmaf(w1, tv, bb));
                    float a = fast_tanh(p);
                    float s = 1.0f - a * a;
                    float v = (ch == 0) ? a : (ch == 1) ? s * w1
                             : (ch == 2) ? s * w0 : -2.0f * a * s * w0 * w0;
                    _Float16 h0, h1; split2(v, h0, h1);
                    v0[i] = h0; v1[i] = h1;
                }
                a0[kt] = v0; a1[kt] = v1;
            }
            half4 t0 = {0, 0, 0, 0}, t1 = {0, 0, 0, 0};
            if (q == 0) {
                #pragma unroll
                for (int i = 0; i < 4; ++i) {
                    int j = 96 + i;
                    float w0 = W1[2*j], w1 = W1[2*j+1], bb = b1[j];
                    float p = fmaf(w0, xv, fmaf(w1, tv, bb));
                    float a = fast_tanh(p);
                    float s = 1.0f - a * a;
                    float v = (ch == 0) ? a : (ch == 1) ? s * w1
                             : (ch == 2) ? s * w0 : -2.0f * a * s * w0 * w0;
                    _Float16 h0, h1; split2(v, h0, h1);
                    t0[i] = h0; t1[i] = h1;
                }
            }
            a0t = t0; a1t = t1;
        }

        // ---------------- 3 hidden GEMMs + transitions ----------------
        for (int l = 0; l < 3; ++l) {
            const char* WL = smem + l * LW;
            const float* BL = (l == 0) ? b2 : (l == 1) ? b3 : b4;

            float p00 = 0.f, p01 = 0.f, p03 = 0.f;   // epilogue accumulators
            float p10 = 0.f, p11 = 0.f, p13 = 0.f;

            // consume-one-jt: transition (l<2, builds n-frags via window) or
            // epilogue partial (l==2). JT must be a LITERAL constant.
            #define CONSUME(JT, C0, C1)                                          \
            {                                                                    \
                int j  = 16 * (JT) + c15;                                        \
                float z0 = (C0)[0] + (C1)[0] * (1.0f/512.0f);                    \
                float z1 = (C0)[1] + (C1)[1] * (1.0f/512.0f);                    \
                float z2 = (C0)[2] + (C1)[2] * (1.0f/512.0f);                    \
                float z3 = (C0)[3] + (C1)[3] * (1.0f/512.0f);                    \
                if (l < 2) {                                                     \
                    float bj = BL[(j < 100) ? j : 99];                           \
                    float a = fast_tanh(z0 + bj);                                \
                    float s = 1.0f - a * a;                                      \
                    float v0 = a, v1 = s * z1, v2 = s * z2;                      \
                    float v3 = fmaf(-2.0f * a * s * z2, z2, s * z3);             \
                    _Float16 h0, h1;                                             \
                    char* bp = win + c15 * 2;                                    \
                    split2(v0, h0, h1);                                          \
                    *(_Float16*)(bp + (4*q+0)*ROWB) = h0;                        \
                    *(_Float16*)(bp + (4*q+0)*ROWB + PLANEB2) = h1;              \
                    split2(v1, h0, h1);                                          \
                    *(_Float16*)(bp + (4*q+1)*ROWB) = h0;                        \
                    *(_Float16*)(bp + (4*q+1)*ROWB + PLANEB2) = h1;              \
                    split2(v2, h0, h1);                                          \
                    *(_Float16*)(bp + (4*q+2)*ROWB) = h0;                        \
                    *(_Float16*)(bp + (4*q+2)*ROWB + PLANEB2) = h1;              \
                    split2(v3, h0, h1);                                          \
                    *(_Float16*)(bp + (4*q+3)*ROWB) = h0;                        \
                    *(_Float16*)(bp + (4*q+3)*ROWB + PLANEB2) = h1;              \
                    if ((JT) < 6) {                                              \
                        const int nidx = ((JT) < 6) ? ((JT) >> 1) : 0;           \
                        const char* rb = win + c15 * ROWB + (q & 1) * 16;        \
                        U8 mu8;                                                  \
                        bool act = ((q >> 1) == ((JT) & 1));                     \
                        mu8.u = *(const uint4*)(rb);                             \
                        if (act) n0[nidx] = mu8.h;                               \
                        mu8.u = *(const uint4*)(rb + PLANEB2);                   \
                        if (act) n1[nidx] = mu8.h;                               \
                    } else {                                                     \
                        const char* rb = win + c15 * ROWB;                       \
                        U4 mu4;                                                  \
                        mu4.u = *(const uint2*)(rb);                             \
                        n0t = (q == 0) ? mu4.h : (half4){0,0,0,0};               \
                        mu4.u = *(const uint2*)(rb + PLANEB2);                   \
                        n1t = (q == 0) ? mu4.h : (half4){0,0,0,0};               \
                    }                                                            \
                } else {                                                         \
                    int j2 = (j < 100) ? j : 99;                                 \
                    float m = (j < 100) ? 1.0f : 0.0f;                           \
                    float bj = BL[j2];                                           \
                    float w50 = W5[j2] * m, w51 = W5[100 + j2] * m;              \
                    float a = fast_tanh(z0 + bj);                                \
                    float s = 1.0f - a * a;                                      \
                    float v0 = a, v1 = s * z1;                                   \
                    float v3 = fmaf(-2.0f * a * s * z2, z2, s * z3);             \
                    p00 = fmaf(w50, v0, p00);                                    \
                    p01 = fmaf(w50, v1, p01);                                    \
                    p03 = fmaf(w50, v3, p03);                                    \
                    p10 = fmaf(w51, v0, p10);                                    \
                    p11 = fmaf(w51, v1, p11);                                    \
                    p13 = fmaf(w51, v3, p13);                                    \
                }                                                                \
            }

            // one jt: 12 MFMAs into a single (c0,c1) pair, B-temps reused.
            #define GEMM_JT(JT)                                                  \
            {                                                                    \
                f32x4 c0 = (f32x4){0.f, 0.f, 0.f, 0.f};                          \
                f32x4 c1 = (f32x4){0.f, 0.f, 0.f, 0.f};                          \
                U8 b0u, b1u;                                                     \
                b0u.u = *(const uint4*)(WL + 0*14336 + (JT)*2048 + lane*16);     \
                b1u.u = *(const uint4*)(WL + 0*14336 + (JT)*2048 + 1024 + lane*16);\
                c0 = __builtin_amdgcn_mfma_f32_16x16x32_f16(a0[0], b0u.h, c0, 0, 0, 0);\
                c1 = __builtin_amdgcn_mfma_f32_16x16x32_f16(a0[0], b1u.h, c1, 0, 0, 0);\
                c1 = __builtin_amdgcn_mfma_f32_16x16x32_f16(a1[0], b0u.h, c1, 0, 0, 0);\
                b0u.u = *(const uint4*)(WL + 1*14336 + (JT)*2048 + lane*16);     \
                b1u.u = *(const uint4*)(WL + 1*14336 + (JT)*2048 + 1024 + lane*16);\
                c0 = __builtin_amdgcn_mfma_f32_16x16x32_f16(a0[1], b0u.h, c0, 0, 0, 0);\
                c1 = __builtin_amdgcn_mfma_f32_16x16x32_f16(a0[1], b1u.h, c1, 0, 0, 0);\
                c1 = __builtin_amdgcn_mfma_f32_16x16x32_f16(a1[1], b0u.h, c1, 0, 0, 0);\
                b0u.u = *(const uint4*)(WL + 2*14336 + (JT)*2048 + lane*16);     \
                b1u.u = *(const uint4*)(WL + 2*14336 + (JT)*2048 + 1024 + lane*16);\
                c0 = __builtin_amdgcn_mfma_f32_16x16x32_f16(a0[2], b0u.h, c0, 0, 0, 0);\
                c1 = __builtin_amdgcn_mfma_f32_16x16x32_f16(a0[2], b1u.h, c1, 0, 0, 0);\
                c1 = __builtin_amdgcn_mfma_f32_16x16x32_f16(a1[2], b0u.h, c1, 0, 0, 0);\
                {                                                                \
                    int toff  = (lane < 16) ? (l*LW + 43008 + (JT)*256 + lane*8) : ZOFF;\
                    int toff1 = (lane < 16) ? (toff + 128) : ZOFF;               \
                    U4 tb0, tb1;                                                 \
                    tb0.u = *(const uint2*)(smem + toff);                        \
                    tb1.u = *(const uint2*)(smem + toff1);                       \
                    c0 = __builtin_amdgcn_mfma_f32_16x16x16f16(a0t, tb0.h, c0, 0, 0, 0);\
                    c1 = __builtin_amdgcn_mfma_f32_16x16x16f16(a0t, tb1.h, c1, 0, 0, 0);\
                    c1 = __builtin_amdgcn_mfma_f32_16x16x16f16(a1t, tb0.h, c1, 0, 0, 0);\
                }                                                                \
                CONSUME(JT, c0, c1);                                             \
            }

            GEMM_JT(0)
            GEMM_JT(1)
            GEMM_JT(2)
            GEMM_JT(3)
            GEMM_JT(4)
            GEMM_JT(5)
            GEMM_JT(6)
            #undef GEMM_JT
            #undef CONSUME

            if (l < 2) {
                a0[0] = n0[0]; a0[1] = n0[1]; a0[2] = n0[2];
                a1[0] = n1[0]; a1[1] = n1[1]; a1[2] = n1[2];
                a0t = n0t; a1t = n1t;
            } else {
                // ---- reduce + NLS residual + store ----
                #pragma unroll
                for (int m = 1; m <= 8; m <<= 1) {
                    p00 += __shfl_xor(p00, m, 64);
                    p01 += __shfl_xor(p01, m, 64);
                    p03 += __shfl_xor(p03, m, 64);
                    p10 += __shfl_xor(p10, m, 64);
                    p11 += __shfl_xor(p11, m, 64);
                    p13 += __shfl_xor(p13, m, 64);
                }
                int pt = chunk * 64 + w * 4 + q;
                if (c15 == 0 && pt < N) {
                    float ur = p00 + b5[0], ui = p10 + b5[1];
                    float mag2 = ur * ur + ui * ui;
                    float fr = fmaf(mag2, ur, fmaf(0.5f, p03, -p11));
                    float fi = fmaf(mag2, ui, fmaf(0.5f, p13,  p01));
                    out[pt]     = fr;
                    out[N + pt] = fi;
                }
            }
        }
    }
}

extern "C" void kernel_launch(void* const* d_in, const int* in_sizes, int n_in,
                              void* d_out, int out_size, void* d_ws, size_t ws_size,
                              hipStream_t stream) {
    const float* x  = (const float*)d_in[0];
    const float* t  = (const float*)d_in[1];
    const float* W1 = (const float*)d_in[2];
    const float* b1 = (const float*)d_in[3];
    const float* W2 = (const float*)d_in[4];
    const float* b2 = (const float*)d_in[5];
    const float* W3 = (const float*)d_in[6];
    const float* b3 = (const float*)d_in[7];
    const float* W4 = (const float*)d_in[8];
    const float* b4 = (const float*)d_in[9];
    const float* W5 = (const float*)d_in[10];
    const float* b5 = (const float*)d_in[11];
    float* out = (float*)d_out;
    const int N = in_sizes[0];
    const int nchunks = (N + 63) / 64;       // 256 cols = 64 points per chunk

    (void)hipFuncSetAttribute((const void*)pinn_mfma,
                              hipFuncAttributeMaxDynamicSharedMemorySize, SMEM_BYTES);

    prep_w<<<84, 64, 0, stream>>>(W2, W3, W4, (unsigned short*)d_ws);
    pinn_mfma<<<256, 1024, SMEM_BYTES, stream>>>(x, t, W1, b1, b2, b3, b4, W5, b5,
                                                 (const char*)d_ws, out, N, nchunks);
}

// Round 8
// 559.450 us; speedup vs baseline: 1.2938x; 1.1814x over previous
//
#include <hip/hip_runtime.h>

// ---------------------------------------------------------------------------
// PINN residual via MFMA (gfx950) — R16: kill the arch-register fight by
// deleting the n-arrays. R15 post-mortem: 1024-thd blocks force a 64/64
// arch/AGPR split; predicated n-frag merges pin 28 regs + temps to the arch
// side (~95 > 64) -> 745 MB scratch. R16: FULL-layer per-wave window
// (6656 B) so a0/a1 are rebuilt AFTER the jt loop (old values dead — no
// second copy, no predication). W no longer fits LDS whole: stage one
// layer (44.8 KB) at a time, barrier-fenced (W is L2-resident; bulk
// coalesced restage, unlike R12's latency-exposed per-MFMA global reads).
// LDS = 44800 W + 16 zero + 16*6656 windows = 151312 B, 16 waves/CU.
// Arch demand ~55-60 <= 64; total ~100 <= 128. Numerics = R7/R8.
// ---------------------------------------------------------------------------

using half8 = __attribute__((ext_vector_type(8))) _Float16;
using half4 = __attribute__((ext_vector_type(4))) _Float16;
using f32x4 = __attribute__((ext_vector_type(4))) float;

#define LW      44800     // bytes of pre-split W per layer (2 planes)
#define WS4     2800      // uint4 per layer
#define ZOFF    44800     // 16-byte zero block (B-frag tail, lanes>=16)
#define WINOFF  44816
#define WINW    6656      // per-wave window bytes: 2 planes x 16 rows x 104 halves
#define ROWH    104       // halves per window row
#define PLANEH  1664      // halves per plane (16 x 104)
#define SMEM_BYTES 151312 // 44816 + 16*6656

union U8 { uint4 u; half8 h; };
union U4 { uint2 u; half4 h; };

static __device__ __forceinline__ float fast_tanh(float z) {
    float e = __expf(2.0f * z);
    return 1.0f - 2.0f * __builtin_amdgcn_rcpf(e + 1.0f);
}

static __device__ __forceinline__ void split2(float v, _Float16& h0, _Float16& h1) {
    h0 = (_Float16)v;
    h1 = (_Float16)((v - (float)h0) * 512.0f);
}

// --------------------------- W pre-split kernel ----------------------------
__global__ void prep_w(const float* __restrict__ W2, const float* __restrict__ W3,
                       const float* __restrict__ W4, unsigned short* __restrict__ ws) {
    int bid = blockIdx.x;
    int l = bid / 28, rem = bid % 28, kt = rem / 7, jt = rem % 7;
    const float* W = (l == 0) ? W2 : (l == 1) ? W3 : W4;
    int lane = threadIdx.x;
    int c = lane & 15, q = lane >> 4;
    int j = 16 * jt + c;
    if (kt < 3) {
        for (int s = 0; s < 2; ++s)
            for (int i = 0; i < 8; ++i) {
                int k = 32 * kt + 8 * q + i;               // <= 95
                float w = (j < 100) ? W[j * 100 + k] : 0.0f;
                _Float16 h0 = (_Float16)w;
                _Float16 val = (s == 0) ? h0 : (_Float16)((w - (float)h0) * 512.0f);
                ws[(l*LW + kt*14336 + jt*2048 + s*1024 + lane*16 + i*2) >> 1] =
                    __builtin_bit_cast(unsigned short, val);
            }
    } else if (lane < 16) {                                 // tail: k=96..99
        for (int s = 0; s < 2; ++s)
            for (int i = 0; i < 4; ++i) {
                int k = 96 + i;
                float w = (j < 100) ? W[j * 100 + k] : 0.0f;
                _Float16 h0 = (_Float16)w;
                _Float16 val = (s == 0) ? h0 : (_Float16)((w - (float)h0) * 512.0f);
                ws[(l*LW + 43008 + jt*256 + s*128 + lane*8 + i*2) >> 1] =
                    __builtin_bit_cast(unsigned short, val);
            }
    }
}

// ------------------------------- main kernel -------------------------------
__global__ void __launch_bounds__(1024) pinn_mfma(
    const float* __restrict__ x,  const float* __restrict__ t,
    const float* __restrict__ W1, const float* __restrict__ b1,
    const float* __restrict__ b2, const float* __restrict__ b3,
    const float* __restrict__ b4,
    const float* __restrict__ W5, const float* __restrict__ b5,
    const char* __restrict__ ws, float* __restrict__ out,
    int N, int nchunks)
{
    extern __shared__ char smem[];
    const int tid  = threadIdx.x;
    const int w    = tid >> 6;           // wave id 0..15
    const int lane = tid & 63;
    const int c15  = lane & 15;
    const int q    = lane >> 4;

    if (tid < 4) ((unsigned*)(smem + ZOFF))[tid] = 0u;   // zero block (persists)

    _Float16* win = (_Float16*)(smem + WINOFF + w * WINW); // [plane:2][row:16][kk:104]

    half8 a0[3], a1[3];                  // current-layer A planes per ktile
    half4 a0t,   a1t;                    // K-tail frags (16x16x16)

    for (int chunk = blockIdx.x; chunk < nchunks; chunk += gridDim.x) {
        const int colbase = chunk * 256 + w * 16;

        // ---------------- layer 1: direct A-frag build ----------------
        {
            int col = colbase + c15;
            int pt = col >> 2, ch = col & 3;
            int ptc = (pt < N) ? pt : (N - 1);
            float xv = x[ptc], tv = t[ptc];
            #pragma unroll
            for (int kt = 0; kt < 3; ++kt) {
                half8 v0, v1;
                #pragma unroll
                for (int i = 0; i < 8; ++i) {
                    int j = 32 * kt + 8 * q + i;           // <= 95
                    float w0 = W1[2*j], w1 = W1[2*j+1], bb = b1[j];
                    float p = fmaf(w0, xv, fmaf(w1, tv, bb));
                    float a = fast_tanh(p);
                    float s = 1.0f - a * a;
                    float v = (ch == 0) ? a : (ch == 1) ? s * w1
                             : (ch == 2) ? s * w0 : -2.0f * a * s * w0 * w0;
                    _Float16 h0, h1; split2(v, h0, h1);
                    v0[i] = h0; v1[i] = h1;
                }
                a0[kt] = v0; a1[kt] = v1;
            }
            half4 t0 = {0, 0, 0, 0}, t1 = {0, 0, 0, 0};
            if (q == 0) {
                #pragma unroll
                for (int i = 0; i < 4; ++i) {
                    int j = 96 + i;
                    float w0 = W1[2*j], w1 = W1[2*j+1], bb = b1[j];
                    float p = fmaf(w0, xv, fmaf(w1, tv, bb));
                    float a = fast_tanh(p);
                    float s = 1.0f - a * a;
                    float v = (ch == 0) ? a : (ch == 1) ? s * w1
                             : (ch == 2) ? s * w0 : -2.0f * a * s * w0 * w0;
                    _Float16 h0, h1; split2(v, h0, h1);
                    t0[i] = h0; t1[i] = h1;
                }
            }
            a0t = t0; a1t = t1;
        }

        // ---------------- 3 hidden GEMMs + transitions ----------------
        for (int l = 0; l < 3; ++l) {
            const float* BL = (l == 0) ? b2 : (l == 1) ? b3 : b4;

            // ---- stage this layer's pre-split W into LDS (barrier-fenced) ----
            __syncthreads();                               // all waves done with prev W
            {
                uint4* wdst = (uint4*)smem;
                const uint4* wsrc = ((const uint4*)ws) + l * WS4;
                for (int i = tid; i < WS4; i += 1024) wdst[i] = wsrc[i];
            }
            __syncthreads();

            float p00 = 0.f, p01 = 0.f, p03 = 0.f;   // epilogue accumulators
            float p10 = 0.f, p11 = 0.f, p13 = 0.f;

            // consume-one-jt: transition writes full window (l<2) or epilogue
            // partial (l==2). JT must be a LITERAL constant.
            #define CONSUME(JT, C0, C1)                                          \
            {                                                                    \
                int j  = 16 * (JT) + c15;                                        \
                float z0 = (C0)[0] + (C1)[0] * (1.0f/512.0f);                    \
                float z1 = (C0)[1] + (C1)[1] * (1.0f/512.0f);                    \
                float z2 = (C0)[2] + (C1)[2] * (1.0f/512.0f);                    \
                float z3 = (C0)[3] + (C1)[3] * (1.0f/512.0f);                    \
                if (l < 2) {                                                     \
                    float bj = BL[(j < 100) ? j : 99];                           \
                    float a = fast_tanh(z0 + bj);                                \
                    float s = 1.0f - a * a;                                      \
                    float v0 = a, v1 = s * z1, v2 = s * z2;                      \
                    float v3 = fmaf(-2.0f * a * s * z2, z2, s * z3);             \
                    if (j < 104) {                                               \
                        _Float16 h0, h1;                                         \
                        _Float16* bp = win + j;                                  \
                        split2(v0, h0, h1);                                      \
                        bp[(4*q+0)*ROWH] = h0;                                   \
                        bp[(4*q+0)*ROWH + PLANEH] = h1;                          \
                        split2(v1, h0, h1);                                      \
                        bp[(4*q+1)*ROWH] = h0;                                   \
                        bp[(4*q+1)*ROWH + PLANEH] = h1;                          \
                        split2(v2, h0, h1);                                      \
                        bp[(4*q+2)*ROWH] = h0;                                   \
                        bp[(4*q+2)*ROWH + PLANEH] = h1;                          \
                        split2(v3, h0, h1);                                      \
                        bp[(4*q+3)*ROWH] = h0;                                   \
                        bp[(4*q+3)*ROWH + PLANEH] = h1;                          \
                    }                                                            \
                } else {                                                         \
                    int j2 = (j < 100) ? j : 99;                                 \
                    float m = (j < 100) ? 1.0f : 0.0f;                           \
                    float bj = BL[j2];                                           \
                    float w50 = W5[j2] * m, w51 = W5[100 + j2] * m;              \
                    float a = fast_tanh(z0 + bj);                                \
                    float s = 1.0f - a * a;                                      \
                    float v0 = a, v1 = s * z1;                                   \
                    float v3 = fmaf(-2.0f * a * s * z2, z2, s * z3);             \
                    p00 = fmaf(w50, v0, p00);                                    \
                    p01 = fmaf(w50, v1, p01);                                    \
                    p03 = fmaf(w50, v3, p03);                                    \
                    p10 = fmaf(w51, v0, p10);                                    \
                    p11 = fmaf(w51, v1, p11);                                    \
                    p13 = fmaf(w51, v3, p13);                                    \
                }                                                                \
            }

            // one jt: 12 MFMAs into a single (c0,c1) pair, B-temps reused.
            #define GEMM_JT(JT)                                                  \
            {                                                                    \
                f32x4 c0 = (f32x4){0.f, 0.f, 0.f, 0.f};                          \
                f32x4 c1 = (f32x4){0.f, 0.f, 0.f, 0.f};                          \
                U8 b0u, b1u;                                                     \
                b0u.u = *(const uint4*)(smem + 0*14336 + (JT)*2048 + lane*16);   \
                b1u.u = *(const uint4*)(smem + 0*14336 + (JT)*2048 + 1024 + lane*16);\
                c0 = __builtin_amdgcn_mfma_f32_16x16x32_f16(a0[0], b0u.h, c0, 0, 0, 0);\
                c1 = __builtin_amdgcn_mfma_f32_16x16x32_f16(a0[0], b1u.h, c1, 0, 0, 0);\
                c1 = __builtin_amdgcn_mfma_f32_16x16x32_f16(a1[0], b0u.h, c1, 0, 0, 0);\
                b0u.u = *(const uint4*)(smem + 1*14336 + (JT)*2048 + lane*16);   \
                b1u.u = *(const uint4*)(smem + 1*14336 + (JT)*2048 + 1024 + lane*16);\
                c0 = __builtin_amdgcn_mfma_f32_16x16x32_f16(a0[1], b0u.h, c0, 0, 0, 0);\
                c1 = __builtin_amdgcn_mfma_f32_16x16x32_f16(a0[1], b1u.h, c1, 0, 0, 0);\
                c1 = __builtin_amdgcn_mfma_f32_16x16x32_f16(a1[1], b0u.h, c1, 0, 0, 0);\
                b0u.u = *(const uint4*)(smem + 2*14336 + (JT)*2048 + lane*16);   \
                b1u.u = *(const uint4*)(smem + 2*14336 + (JT)*2048 + 1024 + lane*16);\
                c0 = __builtin_amdgcn_mfma_f32_16x16x32_f16(a0[2], b0u.h, c0, 0, 0, 0);\
                c1 = __builtin_amdgcn_mfma_f32_16x16x32_f16(a0[2], b1u.h, c1, 0, 0, 0);\
                c1 = __builtin_amdgcn_mfma_f32_16x16x32_f16(a1[2], b0u.h, c1, 0, 0, 0);\
                {                                                                \
                    int toff  = (lane < 16) ? (43008 + (JT)*256 + lane*8) : ZOFF;\
                    int toff1 = (lane < 16) ? (toff + 128) : ZOFF;               \
                    U4 tb0, tb1;                                                 \
                    tb0.u = *(const uint2*)(smem + toff);                        \
                    tb1.u = *(const uint2*)(smem + toff1);                       \
                    c0 = __builtin_amdgcn_mfma_f32_16x16x16f16(a0t, tb0.h, c0, 0, 0, 0);\
                    c1 = __builtin_amdgcn_mfma_f32_16x16x16f16(a0t, tb1.h, c1, 0, 0, 0);\
                    c1 = __builtin_amdgcn_mfma_f32_16x16x16f16(a1t, tb0.h, c1, 0, 0, 0);\
                }                                                                \
                CONSUME(JT, c0, c1);                                             \
            }

            GEMM_JT(0)
            GEMM_JT(1)
            GEMM_JT(2)
            GEMM_JT(3)
            GEMM_JT(4)
            GEMM_JT(5)
            GEMM_JT(6)
            #undef GEMM_JT
            #undef CONSUME

            if (l < 2) {
                // ---- rebuild A-frags from full-layer window (old A dead) ----
                #pragma unroll
                for (int kc = 0; kc < 3; ++kc) {
                    const _Float16* rb = win + c15 * ROWH + 32 * kc + 8 * q;
                    U8 mu8;
                    mu8.u = *(const uint4*)(rb);            a0[kc] = mu8.h;
                    mu8.u = *(const uint4*)(rb + PLANEH);   a1[kc] = mu8.h;
                }
                {
                    U4 mu4;
                    const _Float16* rb = win + c15 * ROWH + 96;
                    mu4.u = *(const uint2*)(rb);            a0t = (q == 0) ? mu4.h : (half4){0,0,0,0};
                    mu4.u = *(const uint2*)(rb + PLANEH);   a1t = (q == 0) ? mu4.h : (half4){0,0,0,0};
                }
            } else {
                // ---- reduce + NLS residual + store ----
                #pragma unroll
                for (int m = 1; m <= 8; m <<= 1) {
                    p00 += __shfl_xor(p00, m, 64);
                    p01 += __shfl_xor(p01, m, 64);
                    p03 += __shfl_xor(p03, m, 64);
                    p10 += __shfl_xor(p10, m, 64);
                    p11 += __shfl_xor(p11, m, 64);
                    p13 += __shfl_xor(p13, m, 64);
                }
                int pt = chunk * 64 + w * 4 + q;
                if (c15 == 0 && pt < N) {
                    float ur = p00 + b5[0], ui = p10 + b5[1];
                    float mag2 = ur * ur + ui * ui;
                    float fr = fmaf(mag2, ur, fmaf(0.5f, p03, -p11));
                    float fi = fmaf(mag2, ui, fmaf(0.5f, p13,  p01));
                    out[pt]     = fr;
                    out[N + pt] = fi;
                }
            }
        }
    }
}

extern "C" void kernel_launch(void* const* d_in, const int* in_sizes, int n_in,
                              void* d_out, int out_size, void* d_ws, size_t ws_size,
                              hipStream_t stream) {
    const float* x  = (const float*)d_in[0];
    const float* t  = (const float*)d_in[1];
    const float* W1 = (const float*)d_in[2];
    const float* b1 = (const float*)d_in[3];
    const float* W2 = (const float*)d_in[4];
    const float* b2 = (const float*)d_in[5];
    const float* W3 = (const float*)d_in[6];
    const float* b3 = (const float*)d_in[7];
    const float* W4 = (const float*)d_in[8];
    const float* b4 = (const float*)d_in[9];
    const float* W5 = (const float*)d_in[10];
    const float* b5 = (const float*)d_in[11];
    float* out = (float*)d_out;
    const int N = in_sizes[0];
    const int nchunks = (N + 63) / 64;       // 256 cols = 64 points per chunk

    (void)hipFuncSetAttribute((const void*)pinn_mfma,
                              hipFuncAttributeMaxDynamicSharedMemorySize, SMEM_BYTES);

    prep_w<<<84, 64, 0, stream>>>(W2, W3, W4, (unsigned short*)d_ws);
    pinn_mfma<<<256, 1024, SMEM_BYTES, stream>>>(x, t, W1, b1, b2, b3, b4, W5, b5,
                                                 (const char*)d_ws, out, N, nchunks);
}